// Round 14
// baseline (333.191 us; speedup 1.0000x reference)
//
#include <hip/hip_runtime.h>

// ClockworkRNN on MI355X — v14: Y-GEMM fused into the serial kernel's idle waves.
// prep/igemm byte-identical to v9..v13 (validated). ygemm dispatch removed.
//
// serial: 8 waves, 1 lgkm-only barrier per round of 8 steps (67 total incl. tail).
//   wave 0: blocks 0,1 (+vmcnt(8)/round store-drain).
//   wave 1: q>=3 ctx tables for blocks 0,1.
//   wave 2: block 2 lag-1 + c02/c12 tables (+vmcnt(0) on odd rounds).
//   waves 3..7: blocks 3..7 lag-2 via depth-4 ring (+vmcnt(0) odd rounds).
//   waves 4..7 ALSO compute Y windows (validated ygemm4 fragment math) on even
//   rounds k in [4,62]: window t0=8(k-4) (16 t x 32 o each), B-frags from Hcomp.
//   Tail: full-drain barrier, then all 8 waves cover windows 30,31 (t=480..511).

typedef unsigned int  u32;
typedef unsigned short u16;
typedef _Float16 f16;
typedef f16   f16x2 __attribute__((ext_vector_type(2)));
typedef f16   f16x8 __attribute__((ext_vector_type(8)));
typedef float f32x4 __attribute__((ext_vector_type(4)));

#define TT   512
#define BB   256
#define NI_  128
#define NO_  128

// ws layout (u32 units) — identical to v4..v13
#define WIP_N   32768
#define WHRP_N  49152   // 24 slots (jj*3+dq) x [64 r][32 pairs], unswizzled
#define WHLP_N  30720   // 15 cold slots x [64 r][8 chunks swizzled][4 pairs]
#define WOA_N   32768
#define ICOMP_PER_B 65280
#define IOFF(j_) (65536 - (65536 >> (j_)))

__device__ __forceinline__ u32 pk2(float a, float b){
  f16x2 v; v.x=(f16)a; v.y=(f16)b; return __builtin_bit_cast(u32, v);
}
__device__ __forceinline__ float tanh_fast(float x){
  float e = __expf(2.0f*x);
  return 1.0f - 2.0f/(e + 1.0f);
}
__device__ __forceinline__ float dot2(u32 a, u32 b, float c){
#if __has_builtin(__builtin_amdgcn_fdot2)
  return __builtin_amdgcn_fdot2(__builtin_bit_cast(f16x2,a), __builtin_bit_cast(f16x2,b), c, false);
#else
  f16x2 x = __builtin_bit_cast(f16x2,a), y = __builtin_bit_cast(f16x2,b);
  c = fmaf((float)x.x,(float)y.x,c); c = fmaf((float)x.y,(float)y.y,c); return c;
#endif
}
__device__ __forceinline__ float f16at_rt(uint4 v, int i){
  u32 w = (i&4) ? ((i&2)? v.w : v.z) : ((i&2)? v.y : v.x);
  w = (i&1) ? (w>>16) : (w & 0xffffu);
  return (float)__builtin_bit_cast(f16, (u16)w);
}
__device__ __forceinline__ float f16at2(uint2 v, int i){
  u32 w = (i&2) ? v.y : v.x;
  w = (i&1) ? (w>>16) : (w & 0xffffu);
  return (float)__builtin_bit_cast(f16, (u16)w);
}
__device__ __forceinline__ float f16at1(u32 v, int i){
  u32 w = i ? (v>>16) : (v & 0xffffu);
  return (float)__builtin_bit_cast(f16, (u16)w);
}

#define BAR()   asm volatile("s_waitcnt lgkmcnt(0)\n\ts_barrier" ::: "memory")
#define LGKMW() do{ asm volatile("s_waitcnt lgkmcnt(0)" ::: "memory"); \
                    __builtin_amdgcn_sched_barrier(0); }while(0)

// ---------------- prep (byte-identical, validated) ----------------
__global__ __launch_bounds__(256) void cw_prep(
    const float* __restrict__ Wi, const float* __restrict__ Wh, const float* __restrict__ Wo,
    u32* __restrict__ WiP, u32* __restrict__ WhrP, u32* __restrict__ WhlP, u32* __restrict__ WoAu,
    float* __restrict__ cb, float* __restrict__ wob)
{
  const int NTOT = WIP_N + WHRP_N + WHLP_N + WOA_N + 512 + 128;
  for (int idx = blockIdx.x*blockDim.x + threadIdx.x; idx < NTOT; idx += (int)(gridDim.x*blockDim.x)){
    if (idx < WIP_N){
      int r  = idx >> 6;
      int c2 = idx & 63;
      WiP[idx] = pk2(Wi[r*129 + 2*c2], Wi[r*129 + 2*c2 + 1]);
    } else if (idx < WIP_N + WHRP_N){
      int q32 = idx - WIP_N;
      int slot = q32 >> 11, rr = (q32 >> 5) & 63, c4 = q32 & 31;
      int jj = slot / 3, dq = slot % 3, qq = jj + dq;
      u32 v = 0u;
      if (qq <= 7){
        int row = 64*jj + rr;
        v = pk2(Wh[row*513 + 64*qq + 2*c4], Wh[row*513 + 64*qq + 2*c4 + 1]);
      }
      WhrP[q32] = v;
    } else if (idx < WIP_N + WHRP_N + WHLP_N){
      int q32 = idx - WIP_N - WHRP_N;
      int slot = q32 >> 11, rr = (q32 >> 5) & 63, pos = (q32 >> 2) & 7, e = q32 & 3;
      int jj, qq;
      if      (slot <  5){ jj = 0; qq = slot + 3; }
      else if (slot <  9){ jj = 1; qq = slot - 1; }
      else if (slot < 12){ jj = 2; qq = slot - 4; }
      else if (slot < 14){ jj = 3; qq = slot - 6; }
      else               { jj = 4; qq = 7; }
      int i  = pos ^ (rr & 7);
      int cp = i*4 + e;
      int row = 64*jj + rr;
      WhlP[q32] = pk2(Wh[row*513 + 64*qq + 2*cp], Wh[row*513 + 64*qq + 2*cp + 1]);
    } else if (idx < WIP_N + WHRP_N + WHLP_N + WOA_N){
      int q32 = idx - WIP_N - WHRP_N - WHLP_N;
      int o = q32 >> 8, kp = q32 & 255;
      WoAu[q32] = pk2(Wo[o*513 + 2*kp], Wo[o*513 + 2*kp + 1]);
    } else if (idx < WIP_N + WHRP_N + WHLP_N + WOA_N + 512){
      int r = idx - WIP_N - WHRP_N - WHLP_N - WOA_N;
      cb[r] = Wh[r*513 + 512] + Wi[r*129 + 128];
    } else {
      int o = idx - WIP_N - WHRP_N - WHLP_N - WOA_N - 512;
      wob[o] = Wo[o*513 + 512];
    }
  }
}

// ---------------- igemm (byte-identical, validated): Icomp [r][Nj m] ----------------
__global__ __launch_bounds__(256) void cw_igemm(
    const float* __restrict__ X, const u32* __restrict__ WiP, f16* __restrict__ Icomp)
{
  const int tid = threadIdx.x;
  const int l = tid & 63, w = tid >> 6;
  const int bid = blockIdx.x;
  const int b = bid / 19, sub = bid % 19;
  int j, m0;
  if      (sub <  8){ j = 0; m0 = sub*64; }
  else if (sub < 12){ j = 1; m0 = (sub-8)*64; }
  else if (sub < 14){ j = 2; m0 = (sub-12)*64; }
  else if (sub ==14){ j = 3; m0 = 0; }
  else              { j = sub-11; m0 = 0; }
  const int Nj = 512 >> j;
  const int mt = m0 + w*16;
  const int la = l & 15, lb = l >> 4;

  int ma = mt + la; if (ma >= Nj) ma = Nj - 1;
  const int t = ma << j;
  const float* Xr = X + ((size_t)t*BB + b)*NI_ + lb*8;
  const u32* wp0 = WiP + (j<<12) + la*64 + lb*4;

  f32x4 a0 = {0.f,0.f,0.f,0.f}, a1 = a0, a2 = a0, a3 = a0;
  #pragma unroll
  for (int ks = 0; ks < 4; ++ks){
    const float4 x0 = *(const float4*)(Xr + ks*32);
    const float4 x1 = *(const float4*)(Xr + ks*32 + 4);
    uint4 au;
    au.x = __builtin_bit_cast(u32, __builtin_amdgcn_cvt_pkrtz(x0.x, x0.y));
    au.y = __builtin_bit_cast(u32, __builtin_amdgcn_cvt_pkrtz(x0.z, x0.w));
    au.z = __builtin_bit_cast(u32, __builtin_amdgcn_cvt_pkrtz(x1.x, x1.y));
    au.w = __builtin_bit_cast(u32, __builtin_amdgcn_cvt_pkrtz(x1.z, x1.w));
    const f16x8 af = __builtin_bit_cast(f16x8, au);
    const u32* wp = wp0 + ks*16;
    a0 = __builtin_amdgcn_mfma_f32_16x16x32_f16(af, __builtin_bit_cast(f16x8, *(const uint4*)(wp       )), a0, 0,0,0);
    a1 = __builtin_amdgcn_mfma_f32_16x16x32_f16(af, __builtin_bit_cast(f16x8, *(const uint4*)(wp + 1024)), a1, 0,0,0);
    a2 = __builtin_amdgcn_mfma_f32_16x16x32_f16(af, __builtin_bit_cast(f16x8, *(const uint4*)(wp + 2048)), a2, 0,0,0);
    a3 = __builtin_amdgcn_mfma_f32_16x16x32_f16(af, __builtin_bit_cast(f16x8, *(const uint4*)(wp + 3072)), a3, 0,0,0);
  }
  const int mb = mt + lb*4;
  if (mb < Nj){
    const size_t offj = 65536 - (65536 >> j);
    f16* base = Icomp + (size_t)b*ICOMP_PER_B + offj + mb;
    uint2 s;
    s.x = __builtin_bit_cast(u32, __builtin_amdgcn_cvt_pkrtz(a0[0], a0[1]));
    s.y = __builtin_bit_cast(u32, __builtin_amdgcn_cvt_pkrtz(a0[2], a0[3]));
    *(uint2*)(base + (size_t)( 0 + la)*Nj) = s;
    s.x = __builtin_bit_cast(u32, __builtin_amdgcn_cvt_pkrtz(a1[0], a1[1]));
    s.y = __builtin_bit_cast(u32, __builtin_amdgcn_cvt_pkrtz(a1[2], a1[3]));
    *(uint2*)(base + (size_t)(16 + la)*Nj) = s;
    s.x = __builtin_bit_cast(u32, __builtin_amdgcn_cvt_pkrtz(a2[0], a2[1]));
    s.y = __builtin_bit_cast(u32, __builtin_amdgcn_cvt_pkrtz(a2[2], a2[3]));
    *(uint2*)(base + (size_t)(32 + la)*Nj) = s;
    s.x = __builtin_bit_cast(u32, __builtin_amdgcn_cvt_pkrtz(a3[0], a3[1]));
    s.y = __builtin_bit_cast(u32, __builtin_amdgcn_cvt_pkrtz(a3[2], a3[3]));
    *(uint2*)(base + (size_t)(48 + la)*Nj) = s;
  }
}

// ---------------- serial v14 ----------------
__device__ __forceinline__ float gemv8(const uint4 (&W)[8], const u32* hq){
  float a0=0.f, a1=0.f, a2=0.f, a3=0.f;
  #pragma unroll
  for (int i = 0; i < 8; ++i){
    const uint4 hv = *(const uint4*)(hq + (i<<2));
    a0 = dot2(W[i].x, hv.x, a0); a1 = dot2(W[i].y, hv.y, a1);
    a2 = dot2(W[i].z, hv.z, a2); a3 = dot2(W[i].w, hv.w, a3);
  }
  return (a0+a1)+(a2+a3);
}
__device__ __forceinline__ float dotreg8(const uint4 (&W)[8], const uint4 (&H)[8]){
  float a0=0.f, a1=0.f, a2=0.f, a3=0.f;
  #pragma unroll
  for (int i = 0; i < 8; ++i){
    a0 = dot2(W[i].x, H[i].x, a0); a1 = dot2(W[i].y, H[i].y, a1);
    a2 = dot2(W[i].z, H[i].z, a2); a3 = dot2(W[i].w, H[i].w, a3);
  }
  return (a0+a1)+(a2+a3);
}
__device__ __forceinline__ float gemv_sw(const u32* __restrict__ wp, const u32* hq, int lx){
  float a0=0.f, a1=0.f, a2=0.f, a3=0.f;
  #pragma unroll
  for (int i = 0; i < 8; ++i){
    const uint4 w  = *(const uint4*)(wp + ((i ^ lx) << 2));
    const uint4 hv = *(const uint4*)(hq + (i<<2));
    a0 = dot2(w.x, hv.x, a0); a1 = dot2(w.y, hv.y, a1);
    a2 = dot2(w.z, hv.z, a2); a3 = dot2(w.w, hv.w, a3);
  }
  return (a0+a1)+(a2+a3);
}
__device__ __forceinline__ float gemv_ns(const u32* __restrict__ wp, const u32* hq){
  float a0=0.f, a1=0.f, a2=0.f, a3=0.f;
  #pragma unroll
  for (int i = 0; i < 8; ++i){
    const uint4 w  = *(const uint4*)(wp + (i << 2));
    const uint4 hv = *(const uint4*)(hq + (i<<2));
    a0 = dot2(w.x, hv.x, a0); a1 = dot2(w.y, hv.y, a1);
    a2 = dot2(w.z, hv.z, a2); a3 = dot2(w.w, hv.w, a3);
  }
  return (a0+a1)+(a2+a3);
}

#define SPR(hr_, q_, s_) ((const u32*)((hr_) + (((((q_)-3)*4) + (int)(s_)) << 6)))

// Y window: 16 timesteps [t0,t0+16) x 32 outputs [opair*32, opair*32+32).
// Verbatim ygemm4 fragment math (validated): B-frags gathered from Hcomp column.
__device__ __forceinline__ void y_window(const f16* __restrict__ HbF,
    const u32* __restrict__ WoAu, const float* __restrict__ wobg,
    float* __restrict__ Y, int b, int t0, int opair, int l)
{
  const int la = l & 15, lb = l >> 4;
  const int o0 = opair * 32;
  const int tA = t0 + la;
  f32x4 ac0 = {0.f,0.f,0.f,0.f}, ac1 = ac0;
  const u32* ap0 = WoAu + (o0 + la)*256 + lb*4;
  #pragma unroll
  for (int ks = 0; ks < 16; ++ks){
    const int j   = ks >> 1;
    const int m   = tA >> j;
    const int off = IOFF(j) + (m << 6) + ((ks & 1) << 5) + lb*8;
    const f16x8 Bf = __builtin_bit_cast(f16x8, *(const uint4*)(HbF + off));
    const f16x8 A0 = __builtin_bit_cast(f16x8, *(const uint4*)(ap0 + ks*16));
    const f16x8 A1 = __builtin_bit_cast(f16x8, *(const uint4*)(ap0 + 16*256 + ks*16));
    ac0 = __builtin_amdgcn_mfma_f32_16x16x32_f16(A0, Bf, ac0, 0,0,0);
    ac1 = __builtin_amdgcn_mfma_f32_16x16x32_f16(A1, Bf, ac1, 0,0,0);
  }
  const float4 wb0 = *(const float4*)(wobg + o0 + lb*4);
  const float4 wb1 = *(const float4*)(wobg + o0 + 16 + lb*4);
  float* Yr = Y + ((size_t)tA*BB + b)*NO_;
  float4 y0, y1;
  y0.x = tanh_fast(ac0[0] + wb0.x); y0.y = tanh_fast(ac0[1] + wb0.y);
  y0.z = tanh_fast(ac0[2] + wb0.z); y0.w = tanh_fast(ac0[3] + wb0.w);
  y1.x = tanh_fast(ac1[0] + wb1.x); y1.y = tanh_fast(ac1[1] + wb1.y);
  y1.z = tanh_fast(ac1[2] + wb1.z); y1.w = tanh_fast(ac1[3] + wb1.w);
  *(float4*)(Yr + o0 + lb*4)      = y0;
  *(float4*)(Yr + o0 + 16 + lb*4) = y1;
}

template<int X>
__device__ __forceinline__ void helper_entries(int per, float* __restrict__ tabp,
    const u32* __restrict__ whr, const u32* __restrict__ whl,
    const u16* __restrict__ hring, int l)
{
  const int lx = l & 7;
  #pragma unroll
  for (int q = 3; q <= 7; ++q){
    if ((per & ((1 << (q-3)) - 1)) == 0){
      const u32 v = ((u32)(8*per) >> q) + 1;
      const u32* hq = SPR(hring, q, v & 3);
      float val;
      if constexpr (X == 0){
        val = gemv_sw(whl + (q-3)*2048 + l*32, hq, lx);
      } else {
        if (q == 3) val = gemv_ns(whr + 5*2048 + l*32, hq);
        else        val = gemv_sw(whl + (5 + (q-4))*2048 + l*32, hq, lx);
      }
      tabp[(X*5 + (q-3))*64 + l] = val;
    }
  }
}

template<int J>
__device__ void run_waveJ(const f16* __restrict__ Ib, const u32* __restrict__ whr,
                          const u32* __restrict__ whl, u16* hring,
                          f16* __restrict__ Hc, float* __restrict__ Hout,
                          float cbv, int r, int b,
                          const f16* __restrict__ HbF, const u32* __restrict__ WoAu,
                          const float* __restrict__ wobg, float* __restrict__ Yp)
{
  constexpr int NJ  = 512 >> J;
  constexpr int ND  = 8 - J;
  constexpr int TWJ = 1 << J;
  const int lx = r & 7;

  uint4 W0[8], W1[8], W2[8];
  {
    const u32* w0 = whr + (J*3)*2048 + r*32;
    #pragma unroll
    for (int i = 0; i < 8; ++i) W0[i] = *(const uint4*)(w0 + (i<<2));
    if constexpr (ND > 1){
      #pragma unroll
      for (int i = 0; i < 8; ++i) W1[i] = *(const uint4*)(w0 + 2048 + (i<<2));
    }
    if constexpr (ND > 2){
      #pragma unroll
      for (int i = 0; i < 8; ++i) W2[i] = *(const uint4*)(w0 + 4096 + (i<<2));
    }
  }
  float ctx[8];
  #pragma unroll
  for (int q = 0; q < 8; ++q) ctx[q] = 0.f;

  uint4 icur = {0,0,0,0}, inxt = {0,0,0,0};
  if constexpr (NJ >= 8) icur = *(const uint4*)(Ib);
  else { const uint2 u2 = *(const uint2*)(Ib); icur.x = u2.x; icur.y = u2.y; }
  if constexpr (NJ > 8) inxt = *(const uint4*)(Ib + 8);

  float h;
  {
    h = tanh_fast(cbv + f16at_rt(icur, 0));
    const f16 h16 = (f16)h;
    hring[(((J-3)*4 + 1) << 6) + r] = __builtin_bit_cast(u16, h16);
    Hc[r] = h16;
    LGKMW();
    ctx[J] = gemv8(W0, SPR(hring, J, 1));
  }

  auto body = [&](int t){
    if ((t & (TWJ - 1)) != 0) return;
    const int tm = t - TWJ;
    const int cc0 = (tm == 0) ? 7 : __builtin_ctz((u32)tm);
    const int cc = cc0 > 7 ? 7 : cc0;
    if constexpr (ND > 1){
      if (cc >= J + 1){ const u32 v = ((u32)tm >> (J + 1)) + 1;
        ctx[J+1] = gemv8(W1, SPR(hring, J+1, v & 3)); }
    }
    if constexpr (ND > 2){
      if (cc >= J + 2){ const u32 v = ((u32)tm >> (J + 2)) + 1;
        ctx[J+2] = gemv8(W2, SPR(hring, J+2, v & 3)); }
    }
    if constexpr (J == 3){
      if (cc >= 6){ const u32 v = ((u32)tm >> 6) + 1; ctx[6] = gemv_sw(whl + 12*2048 + r*32, SPR(hring, 6, v & 3), lx); }
      if (cc >= 7){ const u32 v = ((u32)tm >> 7) + 1; ctx[7] = gemv_sw(whl + 13*2048 + r*32, SPR(hring, 7, v & 3), lx); }
    }
    if constexpr (J == 4){
      if (cc >= 7){ const u32 v = ((u32)tm >> 7) + 1; ctx[7] = gemv_sw(whl + 14*2048 + r*32, SPR(hring, 7, v & 3), lx); }
    }
    const int m = t >> J, e = m & 7;
    if constexpr (NJ > 8){ if (e == 0 && m + 8 < NJ) inxt = *(const uint4*)(Ib + m + 8); }
    float z = cbv + f16at_rt(icur, e);
    #pragma unroll
    for (int q = J; q < 8; ++q) z += ctx[q];
    h = tanh_fast(z);
    const f16 h16 = (f16)h;
    const int sl = (m + 1) & 3;
    hring[(((J-3)*4 + sl) << 6) + r] = __builtin_bit_cast(u16, h16);
    Hc[(m << 6) + r] = h16;
    LGKMW();
    ctx[J] = gemv8(W0, SPR(hring, J, sl));
    if constexpr (NJ > 8){ if (e == 7) icur = inxt; }
  };

  BAR();
  body(8);
  BAR();
  for (int k = 0; k < 64; ++k){
    const int t = 8*(k + 2);
    if (t < 512) body(t);
    if constexpr (J >= 4){
      // fused Y window: t0 = 8(k-4); H needed through t0+15 = 8k-17 (written
      // <= round k-3, drained by the odd-round vmcnt(0)/wave-0 vmcnt(8) discipline).
      if ((k & 1) == 0 && k >= 4 && k <= 62)
        y_window(HbF, WoAu, wobg, Yp, b, 8*(k - 4), J - 4, r);
    }
    if (k & 1) asm volatile("s_waitcnt vmcnt(0)" ::: "memory");
    BAR();
  }
  Hout[(J*64 + r)*BB + b] = h;
}

__global__ __launch_bounds__(512) void cw_serial(
    const f16* __restrict__ Icomp, const u32* __restrict__ WhrP, const u32* __restrict__ WhlP,
    const float* __restrict__ cbg, f16* __restrict__ Hcomp, float* __restrict__ Hout,
    const u32* __restrict__ WoAu, const float* __restrict__ wobg, float* __restrict__ Yp)
{
  __shared__ u32 sW2[6144];
  __shared__ __align__(16) u16 hring[5*4*64];
  __shared__ __align__(16) u16 sh01[128];
  __shared__ __align__(16) u16 sh2[128];
  __shared__ float ctxTab[2*960];
  __shared__ float tab2[512];

  const int tid = (int)threadIdx.x;
  const int b   = (int)blockIdx.x;
  const int wv  = tid >> 6, l = tid & 63;

  for (int i = tid; i < 2048; i += 512){
    const int rr = i >> 5, c4 = i & 31, ch = c4 >> 2, e = c4 & 3;
    const int dst = rr*32 + (((ch ^ rr) & 7) << 2) + e;
    sW2[       dst] = WhrP[2*2048 + i];
    sW2[2048 + dst] = WhrP[4*2048 + i];
    sW2[4096 + dst] = WhrP[6*2048 + i];
  }
  __syncthreads();

  if (wv == 0 || wv == 2) __builtin_amdgcn_s_setprio(1);

  const f16* Ibase = Icomp + (size_t)b*ICOMP_PER_B;
  f16*       Hbase = Hcomp + (size_t)b*ICOMP_PER_B;

  if (wv == 0){
    u16* shw = sh01;
    const u32* shu = (const u32*)sh01;

    uint4 w00[8], w01[8], w11[8];
    #pragma unroll
    for (int i = 0; i < 8; ++i){
      w00[i] = *(const uint4*)(WhrP +      0 + l*32 + (i<<2));
      w01[i] = *(const uint4*)(WhrP +   2048 + l*32 + (i<<2));
      w11[i] = *(const uint4*)(WhrP + 3*2048 + l*32 + (i<<2));
    }
    const float cb0 = cbg[l], cb1 = cbg[64+l];
    float c00=0.f,c01=0.f,c11=0.f,c02=0.f,c12=0.f;
    float c3a[5]={0,0,0,0,0}, c3b[5]={0,0,0,0,0};
    float zq0=cb0, zq1=cb1;
    float h0v=0.f, h1v=0.f;

    const u16* Ib0 = (const u16*)Ibase + l*512;
    const u16* Ib1 = (const u16*)Ibase + 32768 + l*256;
    u16* Hb0 = (u16*)Hbase;
    u16* Hb1 = (u16*)Hbase + 32768;

    uint4 icur0 = *(const uint4*)(Ib0);
    uint2 icur1 = *(const uint2*)(Ib1);

    {
      h0v = tanh_fast(cb0 + f16at_rt(icur0, 0));
      h1v = tanh_fast(cb1 + f16at2(icur1, 0));
      const f16 a0=(f16)h0v, a1=(f16)h1v;
      shw[l]    = __builtin_bit_cast(u16,a0);
      shw[64+l] = __builtin_bit_cast(u16,a1);
      Hb0[l] = __builtin_bit_cast(u16,a0);
      Hb1[l] = __builtin_bit_cast(u16,a1);
      c00 = gemv8(w00, shu);
      uint4 hq1[8];
      #pragma unroll
      for (int i = 0; i < 8; ++i) hq1[i] = *(const uint4*)(shu + 32 + (i<<2));
      c01 = dotreg8(w01, hq1); c11 = dotreg8(w11, hq1);
    }
    BAR();
    BAR();

#define W0_STEP(S_, B1_) do{ \
      const int t_ = 8*k + (S_); \
      float z0 = zq0 + c01 + c02 + c00 + f16at_rt(icur0, (S_)); \
      float z1 = 0.f; \
      if (B1_) z1 = zq1 + c11 + c12 + f16at2(icur1, (S_)>>1); \
      h0v = tanh_fast(z0); \
      if (B1_) h1v = tanh_fast(z1); \
      { const f16 a=(f16)h0v; shw[l] = __builtin_bit_cast(u16,a); \
        Hb0[(t_<<6)+l] = __builtin_bit_cast(u16,a); } \
      if (B1_){ const f16 a=(f16)h1v; shw[64+l] = __builtin_bit_cast(u16,a); \
        Hb1[((4*k+((S_)>>1))<<6)+l] = __builtin_bit_cast(u16,a); } \
      c00 = gemv8(w00, shu); \
      if (B1_){ uint4 hq1[8]; \
        _Pragma("unroll") for (int i = 0; i < 8; ++i) hq1[i] = *(const uint4*)(shu + 32 + (i<<2)); \
        c01 = dotreg8(w01, hq1); c11 = dotreg8(w11, hq1); } \
    }while(0)

    for (int k = 0; k < 64; ++k){
      uint4 inxt0 = icur0; uint2 inxt1 = icur1;
      const bool pf = (k < 63);
      if (pf){
        inxt0 = *(const uint4*)(Ib0 + 8*(k+1));
        inxt1 = *(const uint2*)(Ib1 + 4*(k+1));
      }
      if (k > 0) W0_STEP(0, 1);
      {
        const float* tab = ctxTab + (k & 1)*960;
        /*q=3*/        { c3a[0]=tab[0*64+l]; c3b[0]=tab[5*64+l]; }
        if((k&1)==0)   { c3a[1]=tab[1*64+l]; c3b[1]=tab[6*64+l]; }
        if((k&3)==0)   { c3a[2]=tab[2*64+l]; c3b[2]=tab[7*64+l]; }
        if((k&7)==0)   { c3a[3]=tab[3*64+l]; c3b[3]=tab[8*64+l]; }
        if((k&15)==0)  { c3a[4]=tab[4*64+l]; c3b[4]=tab[9*64+l]; }
        zq0 = cb0 + (((c3a[0]+c3a[1])+(c3a[2]+c3a[3]))+c3a[4]);
        zq1 = cb1 + (((c3b[0]+c3b[1])+(c3b[2]+c3b[3]))+c3b[4]);
      }
      c02 = tab2[(k&1)*256 +   0 + l];
      c12 = tab2[(k&1)*256 +  64 + l];
      W0_STEP(1,0); W0_STEP(2,1); W0_STEP(3,0); W0_STEP(4,1);
      c02 = tab2[(k&1)*256 + 128 + l];
      c12 = tab2[(k&1)*256 + 192 + l];
      W0_STEP(5,0); W0_STEP(6,1); W0_STEP(7,0);
      if (pf){ icur0 = inxt0; icur1 = inxt1; }
      // drain stores older than ~this round (guarantees round k-2 H visible next round)
      asm volatile("s_waitcnt vmcnt(8)" ::: "memory");
      BAR();
    }
#undef W0_STEP
    Hout[l*BB + b]      = h0v;
    Hout[(64+l)*BB + b] = h1v;

  } else if (wv == 1){
    BAR();
    helper_entries<0>(0, ctxTab, WhrP, WhlP, hring, l);
    helper_entries<1>(0, ctxTab, WhrP, WhlP, hring, l);
    BAR();
    for (int k = 0; k < 64; ++k){
      const int per = k + 1;
      if (per < 64){
        float* tp = ctxTab + (per & 1)*960;
        helper_entries<0>(per, tp, WhrP, WhlP, hring, l);
        helper_entries<1>(per, tp, WhrP, WhlP, hring, l);
      }
      BAR();
    }
  } else if (wv == 2){
    const int lx = l & 7;
    uint4 W23r[8], W24r[8];
    #pragma unroll
    for (int i = 0; i < 8; ++i){
      W23r[i] = *(const uint4*)(WhrP + 7*2048 + l*32 + (i<<2));
      W24r[i] = *(const uint4*)(WhrP + 8*2048 + l*32 + (i<<2));
    }
    const float cb2 = cbg[128+l];
    float c22=0.f,c23=0.f,c24=0.f,c25=0.f,c26=0.f,c27=0.f;
    int vp3=0,vp4=0,vp5=0,vp6=0,vp7=0;
    const u16* Ib2 = (const u16*)Ibase + 49152 + l*128;
    u16* Hb2 = (u16*)Hbase + 49152;
    float h2v = 0.f;
    u32 icp = *(const u32*)(Ib2);

    {
      h2v = tanh_fast(cb2 + f16at1(icp, 0));
      const f16 a=(f16)h2v;
      sh2[l] = __builtin_bit_cast(u16,a);
      Hb2[l] = __builtin_bit_cast(u16,a);
      const u32* hb = (const u32*)sh2;
      tab2[  0 + l] = gemv_sw(sW2 +        l*32, hb, lx);
      tab2[ 64 + l] = gemv_sw(sW2 + 2048 + l*32, hb, lx);
    }
    BAR();
    {
      c23 = gemv8(W23r, SPR(hring, 3, 1)); vp3 = 1;
      c24 = gemv8(W24r, SPR(hring, 4, 1)); vp4 = 1;
      c25 = gemv_sw(WhlP +  9*2048 + l*32, SPR(hring, 5, 1), lx); vp5 = 1;
      c26 = gemv_sw(WhlP + 10*2048 + l*32, SPR(hring, 6, 1), lx); vp6 = 1;
      c27 = gemv_sw(WhlP + 11*2048 + l*32, SPR(hring, 7, 1), lx); vp7 = 1;
      c22 = gemv_sw(sW2 + 4096 + l*32, (const u32*)sh2, lx);
      float z2 = cb2 + f16at1(icp, 1) + ((c22 + c23) + (c24 + c25)) + (c26 + c27);
      h2v = tanh_fast(z2);
      const f16 a=(f16)h2v;
      sh2[64+l] = __builtin_bit_cast(u16,a);
      Hb2[64+l] = __builtin_bit_cast(u16,a);
      const u32* hb = (const u32*)(sh2 + 64);
      tab2[128 + l] = gemv_sw(sW2 +        l*32, hb, lx);
      tab2[192 + l] = gemv_sw(sW2 + 2048 + l*32, hb, lx);
    }
    BAR();

    for (int k = 0; k < 64; ++k){
      if (k <= 62){
        const int m1 = 2*(k+1);
        icp = *(const u32*)(Ib2 + m1);
        const int par = (k+1) & 1;
        {
          const int t = m1 << 2;
          { const int v = ((t-1)>>3)+1; if (v != vp3){ c23 = gemv8(W23r, SPR(hring,3,v&3)); vp3 = v; } }
          { const int v = ((t-1)>>4)+1; if (v != vp4){ c24 = gemv8(W24r, SPR(hring,4,v&3)); vp4 = v; } }
          { const int v = ((t-1)>>5)+1; if (v != vp5){ c25 = gemv_sw(WhlP +  9*2048 + l*32, SPR(hring,5,v&3), lx); vp5 = v; } }
          { const int v = ((t-1)>>6)+1; if (v != vp6){ c26 = gemv_sw(WhlP + 10*2048 + l*32, SPR(hring,6,v&3), lx); vp6 = v; } }
          { const int v = ((t-1)>>7)+1; if (v != vp7){ c27 = gemv_sw(WhlP + 11*2048 + l*32, SPR(hring,7,v&3), lx); vp7 = v; } }
          c22 = gemv_sw(sW2 + 4096 + l*32, (const u32*)(sh2 + 64), lx);
          float z2 = cb2 + f16at1(icp, 0) + ((c22 + c23) + (c24 + c25)) + (c26 + c27);
          h2v = tanh_fast(z2);
          const f16 a=(f16)h2v;
          sh2[l] = __builtin_bit_cast(u16,a);
          Hb2[(m1<<6)+l] = __builtin_bit_cast(u16,a);
          const u32* hb = (const u32*)sh2;
          tab2[par*256 +   0 + l] = gemv_sw(sW2 +        l*32, hb, lx);
          tab2[par*256 +  64 + l] = gemv_sw(sW2 + 2048 + l*32, hb, lx);
        }
        {
          const int t = (m1+1) << 2;
          { const int v = ((t-1)>>3)+1; if (v != vp3){ c23 = gemv8(W23r, SPR(hring,3,v&3)); vp3 = v; } }
          { const int v = ((t-1)>>4)+1; if (v != vp4){ c24 = gemv8(W24r, SPR(hring,4,v&3)); vp4 = v; } }
          { const int v = ((t-1)>>5)+1; if (v != vp5){ c25 = gemv_sw(WhlP +  9*2048 + l*32, SPR(hring,5,v&3), lx); vp5 = v; } }
          { const int v = ((t-1)>>6)+1; if (v != vp6){ c26 = gemv_sw(WhlP + 10*2048 + l*32, SPR(hring,6,v&3), lx); vp6 = v; } }
          { const int v = ((t-1)>>7)+1; if (v != vp7){ c27 = gemv_sw(WhlP + 11*2048 + l*32, SPR(hring,7,v&3), lx); vp7 = v; } }
          c22 = gemv_sw(sW2 + 4096 + l*32, (const u32*)sh2, lx);
          float z2 = cb2 + f16at1(icp, 1) + ((c22 + c23) + (c24 + c25)) + (c26 + c27);
          h2v = tanh_fast(z2);
          const f16 a=(f16)h2v;
          sh2[64+l] = __builtin_bit_cast(u16,a);
          Hb2[((m1+1)<<6)+l] = __builtin_bit_cast(u16,a);
          const u32* hb = (const u32*)(sh2 + 64);
          tab2[par*256 + 128 + l] = gemv_sw(sW2 +        l*32, hb, lx);
          tab2[par*256 + 192 + l] = gemv_sw(sW2 + 2048 + l*32, hb, lx);
        }
      }
      if (k & 1) asm volatile("s_waitcnt vmcnt(0)" ::: "memory");
      BAR();
    }
    Hout[(128+l)*BB + b] = h2v;

  } else {
    const int J = wv;
    const float cbv = cbg[J*64 + l];
    const f16* Ib = Ibase + IOFF(J) + l*(512 >> J);
    f16* Hc = Hbase + IOFF(J);
    switch (J){
      case 3: run_waveJ<3>(Ib, WhrP, WhlP, hring, Hc, Hout, cbv, l, b, Hbase, WoAu, wobg, Yp); break;
      case 4: run_waveJ<4>(Ib, WhrP, WhlP, hring, Hc, Hout, cbv, l, b, Hbase, WoAu, wobg, Yp); break;
      case 5: run_waveJ<5>(Ib, WhrP, WhlP, hring, Hc, Hout, cbv, l, b, Hbase, WoAu, wobg, Yp); break;
      case 6: run_waveJ<6>(Ib, WhrP, WhlP, hring, Hc, Hout, cbv, l, b, Hbase, WoAu, wobg, Yp); break;
      default: run_waveJ<7>(Ib, WhrP, WhlP, hring, Hc, Hout, cbv, l, b, Hbase, WoAu, wobg, Yp); break;
    }
  }

  // ---- tail: all H complete; cover Y windows 30,31 (t = 480..511) ----
  asm volatile("s_waitcnt vmcnt(0)" ::: "memory");
  BAR();
  y_window(Hbase, WoAu, wobg, Yp, b, 16*(30 + (wv & 1)), wv >> 1, l);
}

extern "C" void kernel_launch(void* const* d_in, const int* in_sizes, int n_in,
                              void* d_out, int out_size, void* d_ws, size_t ws_size,
                              hipStream_t stream)
{
  const float* X  = (const float*)d_in[0];
  const float* Wi = (const float*)d_in[1];
  const float* Wh = (const float*)d_in[2];
  const float* Wo = (const float*)d_in[3];

  u32*   WiP  = (u32*)d_ws;
  u32*   WhrP = WiP  + WIP_N;
  u32*   WhlP = WhrP + WHRP_N;
  u32*   WoAu = WhlP + WHLP_N;
  float* cb   = (float*)(WoAu + WOA_N);
  float* wob  = cb + 512;
  f16*   Icomp = (f16*)(wob + 128);
  f16*   Hcomp = Icomp + (size_t)BB * ICOMP_PER_B;

  float* Y    = (float*)d_out;
  float* Hout = Y + (size_t)TT*BB*NO_;

  const int prep_n = WIP_N + WHRP_N + WHLP_N + WOA_N + 512 + 128;
  hipLaunchKernelGGL(cw_prep, dim3((prep_n + 255)/256), dim3(256), 0, stream,
                     Wi, Wh, Wo, WiP, WhrP, WhlP, WoAu, cb, wob);

  hipLaunchKernelGGL(cw_igemm, dim3(256*19), dim3(256), 0, stream, X, WiP, Icomp);

  hipLaunchKernelGGL(cw_serial, dim3(BB), dim3(512), 0, stream,
                     Icomp, WhrP, WhlP, cb, Hcomp, Hout, WoAu, wob, Y);
}

// Round 15
// 283.314 us; speedup vs baseline: 1.1760x; 1.1760x over previous
//
#include <hip/hip_runtime.h>

// ClockworkRNN on MI355X — v15: v13 serial (fusion reverted) + ygemm5 (LDS-staged
// Hcomp column, chunk-XOR swizzle, one WG per batch column).
// prep/igemm byte-identical to v9..v14 (validated).

typedef unsigned int  u32;
typedef unsigned short u16;
typedef _Float16 f16;
typedef f16   f16x2 __attribute__((ext_vector_type(2)));
typedef f16   f16x8 __attribute__((ext_vector_type(8)));
typedef float f32x4 __attribute__((ext_vector_type(4)));

#define TT   512
#define BB   256
#define NI_  128
#define NO_  128

// ws layout (u32 units) — identical to v4..v14
#define WIP_N   32768
#define WHRP_N  49152   // 24 slots (jj*3+dq) x [64 r][32 pairs], unswizzled
#define WHLP_N  30720   // 15 cold slots x [64 r][8 chunks swizzled][4 pairs]
#define WOA_N   32768
#define ICOMP_PER_B 65280
#define IOFF(j_) (65536 - (65536 >> (j_)))

#define YG_LDS 130560   // 8160 uint4: full Hcomp column, swizzled

__device__ __forceinline__ u32 pk2(float a, float b){
  f16x2 v; v.x=(f16)a; v.y=(f16)b; return __builtin_bit_cast(u32, v);
}
__device__ __forceinline__ float tanh_fast(float x){
  float e = __expf(2.0f*x);
  return 1.0f - 2.0f/(e + 1.0f);
}
__device__ __forceinline__ float dot2(u32 a, u32 b, float c){
#if __has_builtin(__builtin_amdgcn_fdot2)
  return __builtin_amdgcn_fdot2(__builtin_bit_cast(f16x2,a), __builtin_bit_cast(f16x2,b), c, false);
#else
  f16x2 x = __builtin_bit_cast(f16x2,a), y = __builtin_bit_cast(f16x2,b);
  c = fmaf((float)x.x,(float)y.x,c); c = fmaf((float)x.y,(float)y.y,c); return c;
#endif
}
__device__ __forceinline__ float f16at_rt(uint4 v, int i){
  u32 w = (i&4) ? ((i&2)? v.w : v.z) : ((i&2)? v.y : v.x);
  w = (i&1) ? (w>>16) : (w & 0xffffu);
  return (float)__builtin_bit_cast(f16, (u16)w);
}
__device__ __forceinline__ float f16at2(uint2 v, int i){
  u32 w = (i&2) ? v.y : v.x;
  w = (i&1) ? (w>>16) : (w & 0xffffu);
  return (float)__builtin_bit_cast(f16, (u16)w);
}
__device__ __forceinline__ float f16at1(u32 v, int i){
  u32 w = i ? (v>>16) : (v & 0xffffu);
  return (float)__builtin_bit_cast(f16, (u16)w);
}

#define BAR()   asm volatile("s_waitcnt lgkmcnt(0)\n\ts_barrier" ::: "memory")
#define LGKMW() do{ asm volatile("s_waitcnt lgkmcnt(0)" ::: "memory"); \
                    __builtin_amdgcn_sched_barrier(0); }while(0)

// ---------------- prep (byte-identical, validated) ----------------
__global__ __launch_bounds__(256) void cw_prep(
    const float* __restrict__ Wi, const float* __restrict__ Wh, const float* __restrict__ Wo,
    u32* __restrict__ WiP, u32* __restrict__ WhrP, u32* __restrict__ WhlP, u32* __restrict__ WoAu,
    float* __restrict__ cb, float* __restrict__ wob)
{
  const int NTOT = WIP_N + WHRP_N + WHLP_N + WOA_N + 512 + 128;
  for (int idx = blockIdx.x*blockDim.x + threadIdx.x; idx < NTOT; idx += (int)(gridDim.x*blockDim.x)){
    if (idx < WIP_N){
      int r  = idx >> 6;
      int c2 = idx & 63;
      WiP[idx] = pk2(Wi[r*129 + 2*c2], Wi[r*129 + 2*c2 + 1]);
    } else if (idx < WIP_N + WHRP_N){
      int q32 = idx - WIP_N;
      int slot = q32 >> 11, rr = (q32 >> 5) & 63, c4 = q32 & 31;
      int jj = slot / 3, dq = slot % 3, qq = jj + dq;
      u32 v = 0u;
      if (qq <= 7){
        int row = 64*jj + rr;
        v = pk2(Wh[row*513 + 64*qq + 2*c4], Wh[row*513 + 64*qq + 2*c4 + 1]);
      }
      WhrP[q32] = v;
    } else if (idx < WIP_N + WHRP_N + WHLP_N){
      int q32 = idx - WIP_N - WHRP_N;
      int slot = q32 >> 11, rr = (q32 >> 5) & 63, pos = (q32 >> 2) & 7, e = q32 & 3;
      int jj, qq;
      if      (slot <  5){ jj = 0; qq = slot + 3; }
      else if (slot <  9){ jj = 1; qq = slot - 1; }
      else if (slot < 12){ jj = 2; qq = slot - 4; }
      else if (slot < 14){ jj = 3; qq = slot - 6; }
      else               { jj = 4; qq = 7; }
      int i  = pos ^ (rr & 7);
      int cp = i*4 + e;
      int row = 64*jj + rr;
      WhlP[q32] = pk2(Wh[row*513 + 64*qq + 2*cp], Wh[row*513 + 64*qq + 2*cp + 1]);
    } else if (idx < WIP_N + WHRP_N + WHLP_N + WOA_N){
      int q32 = idx - WIP_N - WHRP_N - WHLP_N;
      int o = q32 >> 8, kp = q32 & 255;
      WoAu[q32] = pk2(Wo[o*513 + 2*kp], Wo[o*513 + 2*kp + 1]);
    } else if (idx < WIP_N + WHRP_N + WHLP_N + WOA_N + 512){
      int r = idx - WIP_N - WHRP_N - WHLP_N - WOA_N;
      cb[r] = Wh[r*513 + 512] + Wi[r*129 + 128];
    } else {
      int o = idx - WIP_N - WHRP_N - WHLP_N - WOA_N - 512;
      wob[o] = Wo[o*513 + 512];
    }
  }
}

// ---------------- igemm (byte-identical, validated): Icomp [r][Nj m] ----------------
__global__ __launch_bounds__(256) void cw_igemm(
    const float* __restrict__ X, const u32* __restrict__ WiP, f16* __restrict__ Icomp)
{
  const int tid = threadIdx.x;
  const int l = tid & 63, w = tid >> 6;
  const int bid = blockIdx.x;
  const int b = bid / 19, sub = bid % 19;
  int j, m0;
  if      (sub <  8){ j = 0; m0 = sub*64; }
  else if (sub < 12){ j = 1; m0 = (sub-8)*64; }
  else if (sub < 14){ j = 2; m0 = (sub-12)*64; }
  else if (sub ==14){ j = 3; m0 = 0; }
  else              { j = sub-11; m0 = 0; }
  const int Nj = 512 >> j;
  const int mt = m0 + w*16;
  const int la = l & 15, lb = l >> 4;

  int ma = mt + la; if (ma >= Nj) ma = Nj - 1;
  const int t = ma << j;
  const float* Xr = X + ((size_t)t*BB + b)*NI_ + lb*8;
  const u32* wp0 = WiP + (j<<12) + la*64 + lb*4;

  f32x4 a0 = {0.f,0.f,0.f,0.f}, a1 = a0, a2 = a0, a3 = a0;
  #pragma unroll
  for (int ks = 0; ks < 4; ++ks){
    const float4 x0 = *(const float4*)(Xr + ks*32);
    const float4 x1 = *(const float4*)(Xr + ks*32 + 4);
    uint4 au;
    au.x = __builtin_bit_cast(u32, __builtin_amdgcn_cvt_pkrtz(x0.x, x0.y));
    au.y = __builtin_bit_cast(u32, __builtin_amdgcn_cvt_pkrtz(x0.z, x0.w));
    au.z = __builtin_bit_cast(u32, __builtin_amdgcn_cvt_pkrtz(x1.x, x1.y));
    au.w = __builtin_bit_cast(u32, __builtin_amdgcn_cvt_pkrtz(x1.z, x1.w));
    const f16x8 af = __builtin_bit_cast(f16x8, au);
    const u32* wp = wp0 + ks*16;
    a0 = __builtin_amdgcn_mfma_f32_16x16x32_f16(af, __builtin_bit_cast(f16x8, *(const uint4*)(wp       )), a0, 0,0,0);
    a1 = __builtin_amdgcn_mfma_f32_16x16x32_f16(af, __builtin_bit_cast(f16x8, *(const uint4*)(wp + 1024)), a1, 0,0,0);
    a2 = __builtin_amdgcn_mfma_f32_16x16x32_f16(af, __builtin_bit_cast(f16x8, *(const uint4*)(wp + 2048)), a2, 0,0,0);
    a3 = __builtin_amdgcn_mfma_f32_16x16x32_f16(af, __builtin_bit_cast(f16x8, *(const uint4*)(wp + 3072)), a3, 0,0,0);
  }
  const int mb = mt + lb*4;
  if (mb < Nj){
    const size_t offj = 65536 - (65536 >> j);
    f16* base = Icomp + (size_t)b*ICOMP_PER_B + offj + mb;
    uint2 s;
    s.x = __builtin_bit_cast(u32, __builtin_amdgcn_cvt_pkrtz(a0[0], a0[1]));
    s.y = __builtin_bit_cast(u32, __builtin_amdgcn_cvt_pkrtz(a0[2], a0[3]));
    *(uint2*)(base + (size_t)( 0 + la)*Nj) = s;
    s.x = __builtin_bit_cast(u32, __builtin_amdgcn_cvt_pkrtz(a1[0], a1[1]));
    s.y = __builtin_bit_cast(u32, __builtin_amdgcn_cvt_pkrtz(a1[2], a1[3]));
    *(uint2*)(base + (size_t)(16 + la)*Nj) = s;
    s.x = __builtin_bit_cast(u32, __builtin_amdgcn_cvt_pkrtz(a2[0], a2[1]));
    s.y = __builtin_bit_cast(u32, __builtin_amdgcn_cvt_pkrtz(a2[2], a2[3]));
    *(uint2*)(base + (size_t)(32 + la)*Nj) = s;
    s.x = __builtin_bit_cast(u32, __builtin_amdgcn_cvt_pkrtz(a3[0], a3[1]));
    s.y = __builtin_bit_cast(u32, __builtin_amdgcn_cvt_pkrtz(a3[2], a3[3]));
    *(uint2*)(base + (size_t)(48 + la)*Nj) = s;
  }
}

// ---------------- serial (v13 verbatim — fusion reverted) ----------------
__device__ __forceinline__ float gemv8(const uint4 (&W)[8], const u32* hq){
  float a0=0.f, a1=0.f, a2=0.f, a3=0.f;
  #pragma unroll
  for (int i = 0; i < 8; ++i){
    const uint4 hv = *(const uint4*)(hq + (i<<2));
    a0 = dot2(W[i].x, hv.x, a0); a1 = dot2(W[i].y, hv.y, a1);
    a2 = dot2(W[i].z, hv.z, a2); a3 = dot2(W[i].w, hv.w, a3);
  }
  return (a0+a1)+(a2+a3);
}
__device__ __forceinline__ float dotreg8(const uint4 (&W)[8], const uint4 (&H)[8]){
  float a0=0.f, a1=0.f, a2=0.f, a3=0.f;
  #pragma unroll
  for (int i = 0; i < 8; ++i){
    a0 = dot2(W[i].x, H[i].x, a0); a1 = dot2(W[i].y, H[i].y, a1);
    a2 = dot2(W[i].z, H[i].z, a2); a3 = dot2(W[i].w, H[i].w, a3);
  }
  return (a0+a1)+(a2+a3);
}
__device__ __forceinline__ float gemv_sw(const u32* __restrict__ wp, const u32* hq, int lx){
  float a0=0.f, a1=0.f, a2=0.f, a3=0.f;
  #pragma unroll
  for (int i = 0; i < 8; ++i){
    const uint4 w  = *(const uint4*)(wp + ((i ^ lx) << 2));
    const uint4 hv = *(const uint4*)(hq + (i<<2));
    a0 = dot2(w.x, hv.x, a0); a1 = dot2(w.y, hv.y, a1);
    a2 = dot2(w.z, hv.z, a2); a3 = dot2(w.w, hv.w, a3);
  }
  return (a0+a1)+(a2+a3);
}
__device__ __forceinline__ float gemv_ns(const u32* __restrict__ wp, const u32* hq){
  float a0=0.f, a1=0.f, a2=0.f, a3=0.f;
  #pragma unroll
  for (int i = 0; i < 8; ++i){
    const uint4 w  = *(const uint4*)(wp + (i << 2));
    const uint4 hv = *(const uint4*)(hq + (i<<2));
    a0 = dot2(w.x, hv.x, a0); a1 = dot2(w.y, hv.y, a1);
    a2 = dot2(w.z, hv.z, a2); a3 = dot2(w.w, hv.w, a3);
  }
  return (a0+a1)+(a2+a3);
}

#define SPR(hr_, q_, s_) ((const u32*)((hr_) + (((((q_)-3)*4) + (int)(s_)) << 6)))

template<int X>
__device__ __forceinline__ void helper_entries(int per, float* __restrict__ tabp,
    const u32* __restrict__ whr, const u32* __restrict__ whl,
    const u16* __restrict__ hring, int l)
{
  const int lx = l & 7;
  #pragma unroll
  for (int q = 3; q <= 7; ++q){
    if ((per & ((1 << (q-3)) - 1)) == 0){
      const u32 v = ((u32)(8*per) >> q) + 1;
      const u32* hq = SPR(hring, q, v & 3);
      float val;
      if constexpr (X == 0){
        val = gemv_sw(whl + (q-3)*2048 + l*32, hq, lx);
      } else {
        if (q == 3) val = gemv_ns(whr + 5*2048 + l*32, hq);
        else        val = gemv_sw(whl + (5 + (q-4))*2048 + l*32, hq, lx);
      }
      tabp[(X*5 + (q-3))*64 + l] = val;
    }
  }
}

template<int J>
__device__ void run_waveJ(const f16* __restrict__ Ib, const u32* __restrict__ whr,
                          const u32* __restrict__ whl, u16* hring,
                          f16* __restrict__ Hc, float* __restrict__ Hout,
                          float cbv, int r, int b)
{
  constexpr int NJ  = 512 >> J;
  constexpr int ND  = 8 - J;
  constexpr int TWJ = 1 << J;
  const int lx = r & 7;

  uint4 W0[8], W1[8], W2[8];
  {
    const u32* w0 = whr + (J*3)*2048 + r*32;
    #pragma unroll
    for (int i = 0; i < 8; ++i) W0[i] = *(const uint4*)(w0 + (i<<2));
    if constexpr (ND > 1){
      #pragma unroll
      for (int i = 0; i < 8; ++i) W1[i] = *(const uint4*)(w0 + 2048 + (i<<2));
    }
    if constexpr (ND > 2){
      #pragma unroll
      for (int i = 0; i < 8; ++i) W2[i] = *(const uint4*)(w0 + 4096 + (i<<2));
    }
  }
  float ctx[8];
  #pragma unroll
  for (int q = 0; q < 8; ++q) ctx[q] = 0.f;

  uint4 icur = {0,0,0,0}, inxt = {0,0,0,0};
  if constexpr (NJ >= 8) icur = *(const uint4*)(Ib);
  else { const uint2 u2 = *(const uint2*)(Ib); icur.x = u2.x; icur.y = u2.y; }
  if constexpr (NJ > 8) inxt = *(const uint4*)(Ib + 8);

  float h;
  {
    h = tanh_fast(cbv + f16at_rt(icur, 0));
    const f16 h16 = (f16)h;
    hring[(((J-3)*4 + 1) << 6) + r] = __builtin_bit_cast(u16, h16);
    Hc[r] = h16;
    LGKMW();
    ctx[J] = gemv8(W0, SPR(hring, J, 1));
  }

  auto body = [&](int t){
    if ((t & (TWJ - 1)) != 0) return;
    const int tm = t - TWJ;
    const int cc0 = (tm == 0) ? 7 : __builtin_ctz((u32)tm);
    const int cc = cc0 > 7 ? 7 : cc0;
    if constexpr (ND > 1){
      if (cc >= J + 1){ const u32 v = ((u32)tm >> (J + 1)) + 1;
        ctx[J+1] = gemv8(W1, SPR(hring, J+1, v & 3)); }
    }
    if constexpr (ND > 2){
      if (cc >= J + 2){ const u32 v = ((u32)tm >> (J + 2)) + 1;
        ctx[J+2] = gemv8(W2, SPR(hring, J+2, v & 3)); }
    }
    if constexpr (J == 3){
      if (cc >= 6){ const u32 v = ((u32)tm >> 6) + 1; ctx[6] = gemv_sw(whl + 12*2048 + r*32, SPR(hring, 6, v & 3), lx); }
      if (cc >= 7){ const u32 v = ((u32)tm >> 7) + 1; ctx[7] = gemv_sw(whl + 13*2048 + r*32, SPR(hring, 7, v & 3), lx); }
    }
    if constexpr (J == 4){
      if (cc >= 7){ const u32 v = ((u32)tm >> 7) + 1; ctx[7] = gemv_sw(whl + 14*2048 + r*32, SPR(hring, 7, v & 3), lx); }
    }
    const int m = t >> J, e = m & 7;
    if constexpr (NJ > 8){ if (e == 0 && m + 8 < NJ) inxt = *(const uint4*)(Ib + m + 8); }
    float z = cbv + f16at_rt(icur, e);
    #pragma unroll
    for (int q = J; q < 8; ++q) z += ctx[q];
    h = tanh_fast(z);
    const f16 h16 = (f16)h;
    const int sl = (m + 1) & 3;
    hring[(((J-3)*4 + sl) << 6) + r] = __builtin_bit_cast(u16, h16);
    Hc[(m << 6) + r] = h16;
    LGKMW();
    ctx[J] = gemv8(W0, SPR(hring, J, sl));
    if constexpr (NJ > 8){ if (e == 7) icur = inxt; }
  };

  BAR();
  body(8);
  BAR();
  for (int k = 0; k < 64; ++k){
    const int t = 8*(k + 2);
    if (t < 512) body(t);
    BAR();
  }
  Hout[(J*64 + r)*BB + b] = h;
}

__global__ __launch_bounds__(512) void cw_serial(
    const f16* __restrict__ Icomp, const u32* __restrict__ WhrP, const u32* __restrict__ WhlP,
    const float* __restrict__ cbg, f16* __restrict__ Hcomp, float* __restrict__ Hout)
{
  __shared__ u32 sW2[6144];
  __shared__ __align__(16) u16 hring[5*4*64];
  __shared__ __align__(16) u16 sh01[128];
  __shared__ __align__(16) u16 sh2[128];
  __shared__ float ctxTab[2*960];
  __shared__ float tab2[512];

  const int tid = (int)threadIdx.x;
  const int b   = (int)blockIdx.x;
  const int wv  = tid >> 6, l = tid & 63;

  for (int i = tid; i < 2048; i += 512){
    const int rr = i >> 5, c4 = i & 31, ch = c4 >> 2, e = c4 & 3;
    const int dst = rr*32 + (((ch ^ rr) & 7) << 2) + e;
    sW2[       dst] = WhrP[2*2048 + i];
    sW2[2048 + dst] = WhrP[4*2048 + i];
    sW2[4096 + dst] = WhrP[6*2048 + i];
  }
  __syncthreads();

  if (wv == 0 || wv == 2) __builtin_amdgcn_s_setprio(1);

  const f16* Ibase = Icomp + (size_t)b*ICOMP_PER_B;
  f16*       Hbase = Hcomp + (size_t)b*ICOMP_PER_B;

  if (wv == 0){
    u16* shw = sh01;
    const u32* shu = (const u32*)sh01;

    uint4 w00[8], w01[8], w11[8];
    #pragma unroll
    for (int i = 0; i < 8; ++i){
      w00[i] = *(const uint4*)(WhrP +      0 + l*32 + (i<<2));
      w01[i] = *(const uint4*)(WhrP +   2048 + l*32 + (i<<2));
      w11[i] = *(const uint4*)(WhrP + 3*2048 + l*32 + (i<<2));
    }
    const float cb0 = cbg[l], cb1 = cbg[64+l];
    float c00=0.f,c01=0.f,c11=0.f,c02=0.f,c12=0.f;
    float c3a[5]={0,0,0,0,0}, c3b[5]={0,0,0,0,0};
    float zq0=cb0, zq1=cb1;
    float h0v=0.f, h1v=0.f;

    const u16* Ib0 = (const u16*)Ibase + l*512;
    const u16* Ib1 = (const u16*)Ibase + 32768 + l*256;
    u16* Hb0 = (u16*)Hbase;
    u16* Hb1 = (u16*)Hbase + 32768;

    uint4 icur0 = *(const uint4*)(Ib0);
    uint2 icur1 = *(const uint2*)(Ib1);

    {
      h0v = tanh_fast(cb0 + f16at_rt(icur0, 0));
      h1v = tanh_fast(cb1 + f16at2(icur1, 0));
      const f16 a0=(f16)h0v, a1=(f16)h1v;
      shw[l]    = __builtin_bit_cast(u16,a0);
      shw[64+l] = __builtin_bit_cast(u16,a1);
      Hb0[l] = __builtin_bit_cast(u16,a0);
      Hb1[l] = __builtin_bit_cast(u16,a1);
      c00 = gemv8(w00, shu);
      uint4 hq1[8];
      #pragma unroll
      for (int i = 0; i < 8; ++i) hq1[i] = *(const uint4*)(shu + 32 + (i<<2));
      c01 = dotreg8(w01, hq1); c11 = dotreg8(w11, hq1);
    }
    BAR();
    BAR();

#define W0_STEP(S_, B1_) do{ \
      const int t_ = 8*k + (S_); \
      float z0 = zq0 + c01 + c02 + c00 + f16at_rt(icur0, (S_)); \
      float z1 = 0.f; \
      if (B1_) z1 = zq1 + c11 + c12 + f16at2(icur1, (S_)>>1); \
      h0v = tanh_fast(z0); \
      if (B1_) h1v = tanh_fast(z1); \
      { const f16 a=(f16)h0v; shw[l] = __builtin_bit_cast(u16,a); \
        Hb0[(t_<<6)+l] = __builtin_bit_cast(u16,a); } \
      if (B1_){ const f16 a=(f16)h1v; shw[64+l] = __builtin_bit_cast(u16,a); \
        Hb1[((4*k+((S_)>>1))<<6)+l] = __builtin_bit_cast(u16,a); } \
      c00 = gemv8(w00, shu); \
      if (B1_){ uint4 hq1[8]; \
        _Pragma("unroll") for (int i = 0; i < 8; ++i) hq1[i] = *(const uint4*)(shu + 32 + (i<<2)); \
        c01 = dotreg8(w01, hq1); c11 = dotreg8(w11, hq1); } \
    }while(0)

    for (int k = 0; k < 64; ++k){
      uint4 inxt0 = icur0; uint2 inxt1 = icur1;
      const bool pf = (k < 63);
      if (pf){
        inxt0 = *(const uint4*)(Ib0 + 8*(k+1));
        inxt1 = *(const uint2*)(Ib1 + 4*(k+1));
      }
      if (k > 0) W0_STEP(0, 1);
      {
        const float* tab = ctxTab + (k & 1)*960;
        /*q=3*/        { c3a[0]=tab[0*64+l]; c3b[0]=tab[5*64+l]; }
        if((k&1)==0)   { c3a[1]=tab[1*64+l]; c3b[1]=tab[6*64+l]; }
        if((k&3)==0)   { c3a[2]=tab[2*64+l]; c3b[2]=tab[7*64+l]; }
        if((k&7)==0)   { c3a[3]=tab[3*64+l]; c3b[3]=tab[8*64+l]; }
        if((k&15)==0)  { c3a[4]=tab[4*64+l]; c3b[4]=tab[9*64+l]; }
        zq0 = cb0 + (((c3a[0]+c3a[1])+(c3a[2]+c3a[3]))+c3a[4]);
        zq1 = cb1 + (((c3b[0]+c3b[1])+(c3b[2]+c3b[3]))+c3b[4]);
      }
      c02 = tab2[(k&1)*256 +   0 + l];
      c12 = tab2[(k&1)*256 +  64 + l];
      W0_STEP(1,0); W0_STEP(2,1); W0_STEP(3,0); W0_STEP(4,1);
      c02 = tab2[(k&1)*256 + 128 + l];
      c12 = tab2[(k&1)*256 + 192 + l];
      W0_STEP(5,0); W0_STEP(6,1); W0_STEP(7,0);
      if (pf){ icur0 = inxt0; icur1 = inxt1; }
      BAR();
    }
#undef W0_STEP
    Hout[l*BB + b]      = h0v;
    Hout[(64+l)*BB + b] = h1v;

  } else if (wv == 1){
    BAR();
    helper_entries<0>(0, ctxTab, WhrP, WhlP, hring, l);
    helper_entries<1>(0, ctxTab, WhrP, WhlP, hring, l);
    BAR();
    for (int k = 0; k < 64; ++k){
      const int per = k + 1;
      if (per < 64){
        float* tp = ctxTab + (per & 1)*960;
        helper_entries<0>(per, tp, WhrP, WhlP, hring, l);
        helper_entries<1>(per, tp, WhrP, WhlP, hring, l);
      }
      BAR();
    }
  } else if (wv == 2){
    const int lx = l & 7;
    uint4 W23r[8], W24r[8];
    #pragma unroll
    for (int i = 0; i < 8; ++i){
      W23r[i] = *(const uint4*)(WhrP + 7*2048 + l*32 + (i<<2));
      W24r[i] = *(const uint4*)(WhrP + 8*2048 + l*32 + (i<<2));
    }
    const float cb2 = cbg[128+l];
    float c22=0.f,c23=0.f,c24=0.f,c25=0.f,c26=0.f,c27=0.f;
    int vp3=0,vp4=0,vp5=0,vp6=0,vp7=0;
    const u16* Ib2 = (const u16*)Ibase + 49152 + l*128;
    u16* Hb2 = (u16*)Hbase + 49152;
    float h2v = 0.f;
    u32 icp = *(const u32*)(Ib2);

    {
      h2v = tanh_fast(cb2 + f16at1(icp, 0));
      const f16 a=(f16)h2v;
      sh2[l] = __builtin_bit_cast(u16,a);
      Hb2[l] = __builtin_bit_cast(u16,a);
      const u32* hb = (const u32*)sh2;
      tab2[  0 + l] = gemv_sw(sW2 +        l*32, hb, lx);
      tab2[ 64 + l] = gemv_sw(sW2 + 2048 + l*32, hb, lx);
    }
    BAR();
    {
      c23 = gemv8(W23r, SPR(hring, 3, 1)); vp3 = 1;
      c24 = gemv8(W24r, SPR(hring, 4, 1)); vp4 = 1;
      c25 = gemv_sw(WhlP +  9*2048 + l*32, SPR(hring, 5, 1), lx); vp5 = 1;
      c26 = gemv_sw(WhlP + 10*2048 + l*32, SPR(hring, 6, 1), lx); vp6 = 1;
      c27 = gemv_sw(WhlP + 11*2048 + l*32, SPR(hring, 7, 1), lx); vp7 = 1;
      c22 = gemv_sw(sW2 + 4096 + l*32, (const u32*)sh2, lx);
      float z2 = cb2 + f16at1(icp, 1) + ((c22 + c23) + (c24 + c25)) + (c26 + c27);
      h2v = tanh_fast(z2);
      const f16 a=(f16)h2v;
      sh2[64+l] = __builtin_bit_cast(u16,a);
      Hb2[64+l] = __builtin_bit_cast(u16,a);
      const u32* hb = (const u32*)(sh2 + 64);
      tab2[128 + l] = gemv_sw(sW2 +        l*32, hb, lx);
      tab2[192 + l] = gemv_sw(sW2 + 2048 + l*32, hb, lx);
    }
    BAR();

    for (int k = 0; k < 64; ++k){
      if (k <= 62){
        const int m1 = 2*(k+1);
        icp = *(const u32*)(Ib2 + m1);
        const int par = (k+1) & 1;
        {
          const int t = m1 << 2;
          { const int v = ((t-1)>>3)+1; if (v != vp3){ c23 = gemv8(W23r, SPR(hring,3,v&3)); vp3 = v; } }
          { const int v = ((t-1)>>4)+1; if (v != vp4){ c24 = gemv8(W24r, SPR(hring,4,v&3)); vp4 = v; } }
          { const int v = ((t-1)>>5)+1; if (v != vp5){ c25 = gemv_sw(WhlP +  9*2048 + l*32, SPR(hring,5,v&3), lx); vp5 = v; } }
          { const int v = ((t-1)>>6)+1; if (v != vp6){ c26 = gemv_sw(WhlP + 10*2048 + l*32, SPR(hring,6,v&3), lx); vp6 = v; } }
          { const int v = ((t-1)>>7)+1; if (v != vp7){ c27 = gemv_sw(WhlP + 11*2048 + l*32, SPR(hring,7,v&3), lx); vp7 = v; } }
          c22 = gemv_sw(sW2 + 4096 + l*32, (const u32*)(sh2 + 64), lx);
          float z2 = cb2 + f16at1(icp, 0) + ((c22 + c23) + (c24 + c25)) + (c26 + c27);
          h2v = tanh_fast(z2);
          const f16 a=(f16)h2v;
          sh2[l] = __builtin_bit_cast(u16,a);
          Hb2[(m1<<6)+l] = __builtin_bit_cast(u16,a);
          const u32* hb = (const u32*)sh2;
          tab2[par*256 +   0 + l] = gemv_sw(sW2 +        l*32, hb, lx);
          tab2[par*256 +  64 + l] = gemv_sw(sW2 + 2048 + l*32, hb, lx);
        }
        {
          const int t = (m1+1) << 2;
          { const int v = ((t-1)>>3)+1; if (v != vp3){ c23 = gemv8(W23r, SPR(hring,3,v&3)); vp3 = v; } }
          { const int v = ((t-1)>>4)+1; if (v != vp4){ c24 = gemv8(W24r, SPR(hring,4,v&3)); vp4 = v; } }
          { const int v = ((t-1)>>5)+1; if (v != vp5){ c25 = gemv_sw(WhlP +  9*2048 + l*32, SPR(hring,5,v&3), lx); vp5 = v; } }
          { const int v = ((t-1)>>6)+1; if (v != vp6){ c26 = gemv_sw(WhlP + 10*2048 + l*32, SPR(hring,6,v&3), lx); vp6 = v; } }
          { const int v = ((t-1)>>7)+1; if (v != vp7){ c27 = gemv_sw(WhlP + 11*2048 + l*32, SPR(hring,7,v&3), lx); vp7 = v; } }
          c22 = gemv_sw(sW2 + 4096 + l*32, (const u32*)sh2, lx);
          float z2 = cb2 + f16at1(icp, 1) + ((c22 + c23) + (c24 + c25)) + (c26 + c27);
          h2v = tanh_fast(z2);
          const f16 a=(f16)h2v;
          sh2[64+l] = __builtin_bit_cast(u16,a);
          Hb2[((m1+1)<<6)+l] = __builtin_bit_cast(u16,a);
          const u32* hb = (const u32*)(sh2 + 64);
          tab2[par*256 + 128 + l] = gemv_sw(sW2 +        l*32, hb, lx);
          tab2[par*256 + 192 + l] = gemv_sw(sW2 + 2048 + l*32, hb, lx);
        }
      }
      BAR();
    }
    Hout[(128+l)*BB + b] = h2v;

  } else {
    const int J = wv;
    const float cbv = cbg[J*64 + l];
    const f16* Ib = Ibase + IOFF(J) + l*(512 >> J);
    f16* Hc = Hbase + IOFF(J);
    switch (J){
      case 3: run_waveJ<3>(Ib, WhrP, WhlP, hring, Hc, Hout, cbv, l, b); break;
      case 4: run_waveJ<4>(Ib, WhrP, WhlP, hring, Hc, Hout, cbv, l, b); break;
      case 5: run_waveJ<5>(Ib, WhrP, WhlP, hring, Hc, Hout, cbv, l, b); break;
      case 6: run_waveJ<6>(Ib, WhrP, WhlP, hring, Hc, Hout, cbv, l, b); break;
      default: run_waveJ<7>(Ib, WhrP, WhlP, hring, Hc, Hout, cbv, l, b); break;
    }
  }
}

// ---------------- ygemm5: LDS-staged Hcomp column, chunk-XOR swizzle ----------------
// grid (BB), 512 thr, dynamic LDS 130560B (pure extern — v4/v5-proven envelope).
// LDS layout: rows of 32 u32 (64 f16); uint4-chunk c of row stored at c^(row&7).
// Wave w: o-pair (w&3) [o-tiles 2(w&3), 2(w&3)+1], t-half (w>>2)*256; 16 windows.
__global__ __launch_bounds__(512) void cw_ygemm5(
    const f16* __restrict__ Hcomp, const u32* __restrict__ WoAu,
    const float* __restrict__ wobg, float* __restrict__ Y)
{
  extern __shared__ u32 sH[];          // 32640 u32
  const int tid = (int)threadIdx.x;
  const int w = tid >> 6, l = tid & 63;
  const int la = l & 15, lb = l >> 4;
  const int b  = (int)blockIdx.x;

  { // stage + swizzle (coalesced global reads; conflict-free LDS writes)
    const uint4* src = (const uint4*)(Hcomp + (size_t)b*ICOMP_PER_B);
    uint4* dst = (uint4*)sH;
    for (int i = tid; i < 8160; i += 512){
      const int row = i >> 3, c = i & 7;
      dst[row*8 + (c ^ (row & 7))] = src[i];
    }
  }
  __syncthreads();

  const int op = (w & 3) * 2;          // first o-tile
  const int t0w = (w >> 2) * 256;      // this wave's t-range

  uint4 A0[16], A1[16];
  {
    const u32* ap = WoAu + (op*16 + la)*256 + lb*4;
    #pragma unroll
    for (int ks = 0; ks < 16; ++ks){
      A0[ks] = *(const uint4*)(ap + ks*16);
      A1[ks] = *(const uint4*)(ap + 16*256 + ks*16);
    }
  }
  const float4 wv0 = *(const float4*)(wobg + op*16 + lb*4);
  const float4 wv1 = *(const float4*)(wobg + (op+1)*16 + lb*4);

  for (int tt = 0; tt < 16; ++tt){
    const int tA = t0w + tt*16 + la;
    f32x4 ac0 = {0.f,0.f,0.f,0.f}, ac1 = ac0;
    #pragma unroll
    for (int ks = 0; ks < 16; ++ks){
      const int j     = ks >> 1;
      const int m     = tA >> j;
      const int row   = (IOFF(j) >> 6) + m;
      const int chunk = ((ks & 1) << 2) + lb;
      const uint4 Bu  = *(const uint4*)(sH + row*32 + ((chunk ^ (row & 7)) << 2));
      const f16x8 Bf  = __builtin_bit_cast(f16x8, Bu);
      ac0 = __builtin_amdgcn_mfma_f32_16x16x32_f16(__builtin_bit_cast(f16x8, A0[ks]), Bf, ac0, 0,0,0);
      ac1 = __builtin_amdgcn_mfma_f32_16x16x32_f16(__builtin_bit_cast(f16x8, A1[ks]), Bf, ac1, 0,0,0);
    }
    float* Yr = Y + ((size_t)tA*BB + b)*NO_;
    float4 y0, y1;
    y0.x = tanh_fast(ac0[0] + wv0.x); y0.y = tanh_fast(ac0[1] + wv0.y);
    y0.z = tanh_fast(ac0[2] + wv0.z); y0.w = tanh_fast(ac0[3] + wv0.w);
    y1.x = tanh_fast(ac1[0] + wv1.x); y1.y = tanh_fast(ac1[1] + wv1.y);
    y1.z = tanh_fast(ac1[2] + wv1.z); y1.w = tanh_fast(ac1[3] + wv1.w);
    *(float4*)(Yr + op*16 + lb*4)     = y0;
    *(float4*)(Yr + (op+1)*16 + lb*4) = y1;
  }
}

extern "C" void kernel_launch(void* const* d_in, const int* in_sizes, int n_in,
                              void* d_out, int out_size, void* d_ws, size_t ws_size,
                              hipStream_t stream)
{
  const float* X  = (const float*)d_in[0];
  const float* Wi = (const float*)d_in[1];
  const float* Wh = (const float*)d_in[2];
  const float* Wo = (const float*)d_in[3];

  u32*   WiP  = (u32*)d_ws;
  u32*   WhrP = WiP  + WIP_N;
  u32*   WhlP = WhrP + WHRP_N;
  u32*   WoAu = WhlP + WHLP_N;
  float* cb   = (float*)(WoAu + WOA_N);
  float* wob  = cb + 512;
  f16*   Icomp = (f16*)(wob + 128);
  f16*   Hcomp = Icomp + (size_t)BB * ICOMP_PER_B;

  float* Y    = (float*)d_out;
  float* Hout = Y + (size_t)TT*BB*NO_;

  const int prep_n = WIP_N + WHRP_N + WHLP_N + WOA_N + 512 + 128;
  hipLaunchKernelGGL(cw_prep, dim3((prep_n + 255)/256), dim3(256), 0, stream,
                     Wi, Wh, Wo, WiP, WhrP, WhlP, WoAu, cb, wob);

  hipLaunchKernelGGL(cw_igemm, dim3(256*19), dim3(256), 0, stream, X, WiP, Icomp);

  hipLaunchKernelGGL(cw_serial, dim3(BB), dim3(512), 0, stream,
                     Icomp, WhrP, WhlP, cb, Hcomp, Hout);

  hipFuncSetAttribute(reinterpret_cast<const void*>(cw_ygemm5),
                      hipFuncAttributeMaxDynamicSharedMemorySize, YG_LDS);
  hipLaunchKernelGGL(cw_ygemm5, dim3(BB), dim3(512), YG_LDS, stream,
                     Hcomp, WoAu, wob, Y);
}